// Round 1
// baseline (309.312 us; speedup 1.0000x reference)
//
#include <hip/hip_runtime.h>
#include <stdint.h>

typedef unsigned short u16;
typedef unsigned int u32;
typedef short bf16x8 __attribute__((ext_vector_type(8)));
typedef float f32x4 __attribute__((ext_vector_type(4)));

#define B_HALF 4096
#define NROWS 8192
#define DCOL 512
#define BM 128
#define BK 32
#define TT 64            // 8192/128
#define NTILES 2080      // TT*(TT+1)/2

__device__ __forceinline__ u16 f2bf(float f) {
  u32 u = __float_as_uint(f);
  u += 0x7fffu + ((u >> 16) & 1u);   // RNE
  return (u16)(u >> 16);
}
__device__ __forceinline__ float bf2f(u16 h) {
  return __uint_as_float(((u32)h) << 16);
}

// ---------- kernel A: per-row sumsq + hi/lo bf16 split ----------
__global__ void rowstats_kernel(const float* __restrict__ src,
                                const float* __restrict__ tgt,
                                u16* __restrict__ hi, u16* __restrict__ lo,
                                float* __restrict__ sq,
                                double* __restrict__ sumsq) {
  int row = blockIdx.x * 4 + (threadIdx.x >> 6);
  int lane = threadIdx.x & 63;
  const float* x = (row < B_HALF) ? (src + (size_t)row * DCOL)
                                  : (tgt + (size_t)(row - B_HALF) * DCOL);
  float4 v0 = *reinterpret_cast<const float4*>(x + lane * 8);
  float4 v1 = *reinterpret_cast<const float4*>(x + lane * 8 + 4);
  float vals[8] = {v0.x, v0.y, v0.z, v0.w, v1.x, v1.y, v1.z, v1.w};
  union { u16 us[8]; uint4 v; } hu, lu;
  float s = 0.f;
#pragma unroll
  for (int q = 0; q < 8; ++q) {
    float f = vals[q];
    s += f * f;
    u16 hb = f2bf(f);
    float hf = bf2f(hb);
    u16 lb = f2bf(f - hf);
    hu.us[q] = hb;
    lu.us[q] = lb;
  }
  size_t off = (size_t)row * DCOL + lane * 8;
  *reinterpret_cast<uint4*>(hi + off) = hu.v;
  *reinterpret_cast<uint4*>(lo + off) = lu.v;
#pragma unroll
  for (int o = 32; o > 0; o >>= 1) s += __shfl_down(s, o);
  if (lane == 0) {
    sq[row] = s;
    atomicAdd(sumsq, (double)s);
  }
}

// ---------- kernel A2: column sums (for closed-form bandwidth) ----------
__global__ void colsum_kernel(const float* __restrict__ src,
                              const float* __restrict__ tgt,
                              float* __restrict__ colsum) {
  int t = threadIdx.x;
  int row0 = blockIdx.x * 256;
  float s0 = 0.f, s1 = 0.f;
#pragma unroll 4
  for (int r = 0; r < 256; ++r) {
    int row = row0 + r;
    const float* x = (row < B_HALF) ? (src + (size_t)row * DCOL)
                                    : (tgt + (size_t)(row - B_HALF) * DCOL);
    s0 += x[t];
    s1 += x[t + 256];
  }
  atomicAdd(&colsum[t], s0);
  atomicAdd(&colsum[t + 256], s1);
}

// ---------- kernel B: bandwidth -> g = -1/(16*bw) ----------
__global__ void bw_kernel(const float* __restrict__ colsum,
                          const double* __restrict__ sumsq,
                          float* __restrict__ gout) {
  int lane = threadIdx.x;
  float cs = 0.f;
#pragma unroll
  for (int q = 0; q < 8; ++q) {
    float c = colsum[lane * 8 + q];
    cs += c * c;
  }
#pragma unroll
  for (int o = 32; o > 0; o >>= 1) cs += __shfl_down(cs, o);
  if (lane == 0) {
    double n = 8192.0;
    double suml2 = 2.0 * n * sumsq[0] - 2.0 * (double)cs;
    double bw = suml2 / (n * n - n);
    gout[0] = (float)(-1.0 / (16.0 * bw));
  }
}

// ---------- kernel C: triangle-tiled MFMA Gram + fused MMD epilogue ----------
__global__ __launch_bounds__(256) void mmd_gemm_kernel(
    const u16* __restrict__ hi, const u16* __restrict__ lo,
    const float* __restrict__ sq, const float* __restrict__ gptr,
    double* __restrict__ acc_out) {
  __shared__ __align__(16) u16 sA_hi[BM * BK];
  __shared__ __align__(16) u16 sA_lo[BM * BK];
  __shared__ __align__(16) u16 sB_hi[BM * BK];
  __shared__ __align__(16) u16 sB_lo[BM * BK];
  __shared__ float sqR[BM], sqC[BM];

  // bijective XCD swizzle (2080 % 8 == 0), then linear-index -> triangle (I<=J)
  int bid = blockIdx.x;
  int t = (bid & 7) * (NTILES / 8) + (bid >> 3);
  int I = 0, rem = t;
  while (rem >= TT - I) { rem -= TT - I; ++I; }
  int J = I + rem;
  int rowStart = I * BM, colStart = J * BM;

  int tid = threadIdx.x;
  int lane = tid & 63, wid = tid >> 6;
  int wr = wid >> 1, wc = wid & 1;

  if (tid < BM) sqR[tid] = sq[rowStart + tid];
  else sqC[tid - BM] = sq[colStart + (tid - BM)];

  f32x4 acc[4][4];
#pragma unroll
  for (int m = 0; m < 4; ++m)
#pragma unroll
    for (int n = 0; n < 4; ++n) acc[m][n] = (f32x4){0.f, 0.f, 0.f, 0.f};

  // staging roles: wave 0 -> A_hi, 1 -> A_lo, 2 -> B_hi, 3 -> B_lo
  const u16* gbase = (wid & 1) ? lo : hi;
  int rstart = (wid < 2) ? rowStart : colStart;
  u16* ldsBase = (wid == 0) ? sA_hi : (wid == 1) ? sA_lo : (wid == 2) ? sB_hi : sB_lo;
  int rowInIssue = lane >> 2;                       // 0..15
  int cSwz = (lane & 3) ^ ((lane >> 3) & 3);        // chunk ^ ((row>>1)&3)
  const u16* gp0 = gbase + (size_t)(rstart + rowInIssue) * DCOL + cSwz * 8;

  int r15 = lane & 15, kbk = lane >> 4;
  int fragOff = (kbk ^ ((r15 >> 1) & 3)) * 8;       // undo the staging swizzle

  for (int kk = 0; kk < DCOL; kk += BK) {
#pragma unroll
    for (int s = 0; s < 8; ++s) {
      const u16* gp = gp0 + kk + (size_t)s * 16 * DCOL;
      u16* lp = ldsBase + s * 512;                  // wave-uniform; HW adds lane*16B
      __builtin_amdgcn_global_load_lds(
          (const __attribute__((address_space(1))) void*)gp,
          (__attribute__((address_space(3))) void*)lp, 16, 0, 0);
    }
    __syncthreads();

    bf16x8 ah[4], al[4], bh[4], bl[4];
#pragma unroll
    for (int m = 0; m < 4; ++m) {
      int row = wr * 64 + m * 16 + r15;
      ah[m] = *reinterpret_cast<const bf16x8*>(sA_hi + row * BK + fragOff);
      al[m] = *reinterpret_cast<const bf16x8*>(sA_lo + row * BK + fragOff);
    }
#pragma unroll
    for (int n = 0; n < 4; ++n) {
      int col = wc * 64 + n * 16 + r15;
      bh[n] = *reinterpret_cast<const bf16x8*>(sB_hi + col * BK + fragOff);
      bl[n] = *reinterpret_cast<const bf16x8*>(sB_lo + col * BK + fragOff);
    }
#pragma unroll
    for (int m = 0; m < 4; ++m)
#pragma unroll
      for (int n = 0; n < 4; ++n) {
        acc[m][n] = __builtin_amdgcn_mfma_f32_16x16x32_bf16(ah[m], bh[n], acc[m][n], 0, 0, 0);
        acc[m][n] = __builtin_amdgcn_mfma_f32_16x16x32_bf16(ah[m], bl[n], acc[m][n], 0, 0, 0);
        acc[m][n] = __builtin_amdgcn_mfma_f32_16x16x32_bf16(al[m], bh[n], acc[m][n], 0, 0, 0);
      }
    __syncthreads();
  }

  // fused epilogue: l2 -> sum_k exp(-l2/(bw*2^k)) = u + u^2 + u^4 + u^8 + u^16
  float gf = gptr[0];
  float partial = 0.f;
  int rbase = (lane >> 4) * 4;
  int cidx = lane & 15;
#pragma unroll
  for (int m = 0; m < 4; ++m) {
    float sr[4];
#pragma unroll
    for (int e = 0; e < 4; ++e) sr[e] = sqR[wr * 64 + m * 16 + rbase + e];
#pragma unroll
    for (int n = 0; n < 4; ++n) {
      float sc = sqC[wc * 64 + n * 16 + cidx];
#pragma unroll
      for (int e = 0; e < 4; ++e) {
        float d = acc[m][n][e];
        float l2v = sr[e] + sc - 2.f * d;
        float u = __expf(gf * l2v);
        float u2 = u * u, u4 = u2 * u2, u8 = u4 * u4, u16v = u8 * u8;
        partial += u + u2 + u4 + u8 + u16v;
      }
    }
  }
  float wsign = ((I == J) ? 1.f : 2.f) *
                (((rowStart < B_HALF) == (colStart < B_HALF)) ? 1.f : -1.f);
  partial *= wsign;
#pragma unroll
  for (int o = 32; o > 0; o >>= 1) partial += __shfl_down(partial, o);
  if (lane == 0) atomicAdd(acc_out, (double)partial);
}

// ---------- kernel D: finalize ----------
__global__ void finalize_kernel(const double* __restrict__ acc, float* __restrict__ out) {
  out[0] = (float)(acc[0] / (4096.0 * 4096.0));
}

extern "C" void kernel_launch(void* const* d_in, const int* in_sizes, int n_in,
                              void* d_out, int out_size, void* d_ws, size_t ws_size,
                              hipStream_t stream) {
  const float* src = (const float*)d_in[0];
  const float* tgt = (const float*)d_in[1];
  char* ws = (char*)d_ws;

  double* accp   = (double*)(ws + 0);
  double* sumsqp = (double*)(ws + 8);
  float*  gp     = (float*)(ws + 16);
  float*  colsum = (float*)(ws + 64);
  float*  sqp    = (float*)(ws + 4096);
  u16*    hi     = (u16*)(ws + 65536);
  u16*    lo     = (u16*)(ws + 65536 + (size_t)NROWS * DCOL * 2);

  // zero accumulators (acc, sumsq, g, colsum). Everything else is overwritten.
  hipMemsetAsync(ws, 0, 4096, stream);

  rowstats_kernel<<<NROWS / 4, 256, 0, stream>>>(src, tgt, hi, lo, sqp, sumsqp);
  colsum_kernel<<<NROWS / 256, 256, 0, stream>>>(src, tgt, colsum);
  bw_kernel<<<1, 64, 0, stream>>>(colsum, sumsqp, gp);
  mmd_gemm_kernel<<<NTILES, 256, 0, stream>>>(hi, lo, sqp, gp, accp);
  finalize_kernel<<<1, 1, 0, stream>>>(accp, (float*)d_out);
}

// Round 2
// 115.081 us; speedup vs baseline: 2.6878x; 2.6878x over previous
//
#include <hip/hip_runtime.h>
#include <stdint.h>

typedef unsigned short u16;
typedef unsigned int u32;
typedef _Float16 f16;
typedef _Float16 f16x8 __attribute__((ext_vector_type(8)));
typedef float f32x4 __attribute__((ext_vector_type(4)));

#define B_HALF 4096
#define NROWS 8192
#define DCOL 512
#define BM 128
#define BK 32
#define TT 64            // 8192/128
#define NTILES 2080      // TT*(TT+1)/2

// ---------- kernel A: per-row sumsq + fp16 cast ----------
__global__ void rowstats_kernel(const float* __restrict__ src,
                                const float* __restrict__ tgt,
                                u16* __restrict__ hp,
                                float* __restrict__ sq) {
  int row = blockIdx.x * 4 + (threadIdx.x >> 6);
  int lane = threadIdx.x & 63;
  const float* x = (row < B_HALF) ? (src + (size_t)row * DCOL)
                                  : (tgt + (size_t)(row - B_HALF) * DCOL);
  float4 v0 = *reinterpret_cast<const float4*>(x + lane * 8);
  float4 v1 = *reinterpret_cast<const float4*>(x + lane * 8 + 4);
  float vals[8] = {v0.x, v0.y, v0.z, v0.w, v1.x, v1.y, v1.z, v1.w};
  union { f16 h[8]; uint4 v; } hu;
  float s = 0.f;
#pragma unroll
  for (int q = 0; q < 8; ++q) {
    float f = vals[q];
    s += f * f;
    hu.h[q] = (f16)f;          // v_cvt_f16_f32, RNE
  }
  size_t off = (size_t)row * DCOL + lane * 8;
  *reinterpret_cast<uint4*>(hp + off) = hu.v;
#pragma unroll
  for (int o = 32; o > 0; o >>= 1) s += __shfl_down(s, o);
  if (lane == 0) sq[row] = s;
}

// ---------- kernel A2: column sums (for closed-form bandwidth) ----------
__global__ void colsum_kernel(const float* __restrict__ src,
                              const float* __restrict__ tgt,
                              float* __restrict__ colsum) {
  int t = threadIdx.x;
  int row0 = blockIdx.x * 256;
  float s0 = 0.f, s1 = 0.f;
#pragma unroll 4
  for (int r = 0; r < 256; ++r) {
    int row = row0 + r;
    const float* x = (row < B_HALF) ? (src + (size_t)row * DCOL)
                                    : (tgt + (size_t)(row - B_HALF) * DCOL);
    s0 += x[t];
    s1 += x[t + 256];
  }
  atomicAdd(&colsum[t], s0);       // 512 addresses x 32 blocks: low contention
  atomicAdd(&colsum[t + 256], s1);
}

// ---------- kernel B: bandwidth -> g = -1/(16*bw) ----------
__global__ void bw_kernel(const float* __restrict__ colsum,
                          const float* __restrict__ sq,
                          float* __restrict__ gout) {
  __shared__ double red[256];
  int tid = threadIdx.x;
  double ssq = 0.0;
  for (int i = tid; i < NROWS; i += 256) ssq += (double)sq[i];
  double scs = 0.0;
  for (int c = tid; c < DCOL; c += 256) {
    double v = (double)colsum[c];
    scs += v * v;
  }
  red[tid] = ssq;
  __syncthreads();
  for (int o = 128; o > 0; o >>= 1) {
    if (tid < o) red[tid] += red[tid + o];
    __syncthreads();
  }
  double sumsq = red[0];
  __syncthreads();
  red[tid] = scs;
  __syncthreads();
  for (int o = 128; o > 0; o >>= 1) {
    if (tid < o) red[tid] += red[tid + o];
    __syncthreads();
  }
  if (tid == 0) {
    double n = (double)NROWS;
    double suml2 = 2.0 * n * sumsq - 2.0 * red[0];
    double bw = suml2 / (n * n - n);
    gout[0] = (float)(-1.0 / (16.0 * bw));
  }
}

// ---------- kernel C: triangle-tiled fp16 MFMA Gram + fused MMD epilogue ----------
__global__ __launch_bounds__(256) void mmd_gemm_kernel(
    const u16* __restrict__ hp,
    const float* __restrict__ sq, const float* __restrict__ gptr,
    float* __restrict__ partials) {
  __shared__ __align__(16) u16 sA[BM * BK];
  __shared__ __align__(16) u16 sB[BM * BK];
  __shared__ float sqR[BM], sqC[BM];

  // bijective XCD swizzle (2080 % 8 == 0), then linear-index -> triangle (I<=J)
  int bid = blockIdx.x;
  int t = (bid & 7) * (NTILES / 8) + (bid >> 3);
  int I = 0, rem = t;
  while (rem >= TT - I) { rem -= TT - I; ++I; }
  int J = I + rem;
  int rowStart = I * BM, colStart = J * BM;

  int tid = threadIdx.x;
  int lane = tid & 63, wid = tid >> 6;
  int wr = wid >> 1, wc = wid & 1;

  if (tid < BM) sqR[tid] = sq[rowStart + tid];
  else sqC[tid - BM] = sq[colStart + (tid - BM)];

  f32x4 acc[4][4];
#pragma unroll
  for (int m = 0; m < 4; ++m)
#pragma unroll
    for (int n = 0; n < 4; ++n) acc[m][n] = (f32x4){0.f, 0.f, 0.f, 0.f};

  // staging roles: waves 0,1 -> A rows [wid*64,+64); waves 2,3 -> B
  int w1 = wid & 1;
  int rstart = (wid < 2) ? rowStart : colStart;
  u16* ldsBase = ((wid < 2) ? sA : sB) + w1 * 64 * BK;
  int rowInIssue = lane >> 2;                       // 0..15
  int cSwz = (lane & 3) ^ ((lane >> 3) & 3);        // chunk ^ ((row>>1)&3)
  const u16* gp0 = hp + (size_t)(rstart + w1 * 64 + rowInIssue) * DCOL + cSwz * 8;

  int r15 = lane & 15, kbk = lane >> 4;
  int fragOff = (kbk ^ ((r15 >> 1) & 3)) * 8;       // undo the staging swizzle

  for (int kk = 0; kk < DCOL; kk += BK) {
#pragma unroll
    for (int s = 0; s < 4; ++s) {
      const u16* gp = gp0 + kk + (size_t)s * 16 * DCOL;
      u16* lp = ldsBase + s * 512;                  // wave-uniform; HW adds lane*16B
      __builtin_amdgcn_global_load_lds(
          (const __attribute__((address_space(1))) void*)gp,
          (__attribute__((address_space(3))) void*)lp, 16, 0, 0);
    }
    __syncthreads();

    f16x8 av[4], bv[4];
#pragma unroll
    for (int m = 0; m < 4; ++m) {
      int row = wr * 64 + m * 16 + r15;
      av[m] = *reinterpret_cast<const f16x8*>(sA + row * BK + fragOff);
    }
#pragma unroll
    for (int n = 0; n < 4; ++n) {
      int col = wc * 64 + n * 16 + r15;
      bv[n] = *reinterpret_cast<const f16x8*>(sB + col * BK + fragOff);
    }
#pragma unroll
    for (int m = 0; m < 4; ++m)
#pragma unroll
      for (int n = 0; n < 4; ++n)
        acc[m][n] = __builtin_amdgcn_mfma_f32_16x16x32_f16(av[m], bv[n], acc[m][n], 0, 0, 0);
    __syncthreads();
  }

  // fused epilogue: l2 -> sum_k exp(-l2/(bw*2^k)) = u + u^2 + u^4 + u^8 + u^16
  float gf = gptr[0];
  float partial = 0.f;
  int rbase = (lane >> 4) * 4;
  int cidx = lane & 15;
#pragma unroll
  for (int m = 0; m < 4; ++m) {
    float sr[4];
#pragma unroll
    for (int e = 0; e < 4; ++e) sr[e] = sqR[wr * 64 + m * 16 + rbase + e];
#pragma unroll
    for (int n = 0; n < 4; ++n) {
      float sc = sqC[wc * 64 + n * 16 + cidx];
#pragma unroll
      for (int e = 0; e < 4; ++e) {
        float d = acc[m][n][e];
        float l2v = sr[e] + sc - 2.f * d;
        float u = __expf(gf * l2v);
        float u2 = u * u, u4 = u2 * u2, u8 = u4 * u4, u16v = u8 * u8;
        partial += u + u2 + u4 + u8 + u16v;
      }
    }
  }
  float wsign = ((I == J) ? 1.f : 2.f) *
                (((rowStart < B_HALF) == (colStart < B_HALF)) ? 1.f : -1.f);
  partial *= wsign;
#pragma unroll
  for (int o = 32; o > 0; o >>= 1) partial += __shfl_down(partial, o);
  if (lane == 0) partials[bid * 4 + wid] = partial;   // no same-address atomics
}

// ---------- kernel D: deterministic finalize ----------
__global__ void finalize_kernel(const float* __restrict__ partials,
                                float* __restrict__ out) {
  __shared__ double red[256];
  int tid = threadIdx.x;
  double s = 0.0;
  for (int i = tid; i < NTILES * 4; i += 256) s += (double)partials[i];
  red[tid] = s;
  __syncthreads();
  for (int o = 128; o > 0; o >>= 1) {
    if (tid < o) red[tid] += red[tid + o];
    __syncthreads();
  }
  if (tid == 0) out[0] = (float)(red[0] / (4096.0 * 4096.0));
}

extern "C" void kernel_launch(void* const* d_in, const int* in_sizes, int n_in,
                              void* d_out, int out_size, void* d_ws, size_t ws_size,
                              hipStream_t stream) {
  const float* src = (const float*)d_in[0];
  const float* tgt = (const float*)d_in[1];
  char* ws = (char*)d_ws;

  float* colsum   = (float*)(ws + 0);        // 512 f32 = 2 KB (memset to 0)
  float* gp       = (float*)(ws + 2048);     // 1 f32
  float* sqp      = (float*)(ws + 4096);     // 8192 f32 = 32 KB
  float* partials = (float*)(ws + 36864);    // 8320 f32 ~ 33 KB
  u16*   hp       = (u16*)(ws + 131072);     // 8192*512 fp16 = 8.39 MB

  hipMemsetAsync(ws, 0, 4096, stream);       // zero colsum (+g)

  rowstats_kernel<<<NROWS / 4, 256, 0, stream>>>(src, tgt, hp, sqp);
  colsum_kernel<<<NROWS / 256, 256, 0, stream>>>(src, tgt, colsum);
  bw_kernel<<<1, 256, 0, stream>>>(colsum, sqp, gp);
  mmd_gemm_kernel<<<NTILES, 256, 0, stream>>>(hp, sqp, gp, partials);
  finalize_kernel<<<1, 256, 0, stream>>>(partials, (float*)d_out);
}

// Round 3
// 100.910 us; speedup vs baseline: 3.0652x; 1.1404x over previous
//
#include <hip/hip_runtime.h>
#include <stdint.h>

typedef unsigned short u16;
typedef _Float16 f16;
typedef _Float16 f16x8 __attribute__((ext_vector_type(8)));
typedef float f32x4 __attribute__((ext_vector_type(4)));

#define B_HALF 4096
#define NROWS 8192
#define DCOL 512
#define BM 128
#define BK 64
#define TT 64            // 8192/128
#define NTILES 2080      // TT*(TT+1)/2
#define KSTEPS 8         // DCOL/BK

// ---------- kernel A: fused per-row sumsq + fp16 cast + column sums ----------
__global__ __launch_bounds__(256) void prep_kernel(const float* __restrict__ src,
    const float* __restrict__ tgt, u16* __restrict__ hp,
    float* __restrict__ sq, float* __restrict__ colsum) {
  __shared__ float cs[4][DCOL];
  int lane = threadIdx.x & 63, wid = threadIdx.x >> 6;
  float cpart[8] = {0.f,0.f,0.f,0.f,0.f,0.f,0.f,0.f};
  int row0 = blockIdx.x * 16;
#pragma unroll
  for (int r = 0; r < 4; ++r) {
    int row = row0 + r * 4 + wid;
    const float* x = (row < B_HALF) ? (src + (size_t)row * DCOL)
                                    : (tgt + (size_t)(row - B_HALF) * DCOL);
    float4 v0 = *reinterpret_cast<const float4*>(x + lane * 8);
    float4 v1 = *reinterpret_cast<const float4*>(x + lane * 8 + 4);
    float vals[8] = {v0.x, v0.y, v0.z, v0.w, v1.x, v1.y, v1.z, v1.w};
    union { f16 h[8]; uint4 v; } hu;
    float s = 0.f;
#pragma unroll
    for (int q = 0; q < 8; ++q) {
      float f = vals[q];
      s += f * f;
      cpart[q] += f;
      hu.h[q] = (f16)f;        // v_cvt_f16_f32, RNE
    }
    *reinterpret_cast<uint4*>(hp + (size_t)row * DCOL + lane * 8) = hu.v;
#pragma unroll
    for (int o = 32; o > 0; o >>= 1) s += __shfl_down(s, o);
    if (lane == 0) sq[row] = s;
  }
#pragma unroll
  for (int q = 0; q < 8; ++q) cs[wid][lane * 8 + q] = cpart[q];
  __syncthreads();
  int c = threadIdx.x;
  atomicAdd(&colsum[c],       cs[0][c]       + cs[1][c]       + cs[2][c]       + cs[3][c]);
  atomicAdd(&colsum[c + 256], cs[0][c + 256] + cs[1][c + 256] + cs[2][c + 256] + cs[3][c + 256]);
}

// ---------- kernel B: bandwidth -> g = -1/(16*bw) ----------
__global__ void bw_kernel(const float* __restrict__ colsum,
                          const float* __restrict__ sq,
                          float* __restrict__ gout) {
  __shared__ double red[256];
  int tid = threadIdx.x;
  double ssq = 0.0;
  for (int i = tid; i < NROWS; i += 256) ssq += (double)sq[i];
  double scs = 0.0;
  for (int c = tid; c < DCOL; c += 256) {
    double v = (double)colsum[c];
    scs += v * v;
  }
  red[tid] = ssq;
  __syncthreads();
  for (int o = 128; o > 0; o >>= 1) {
    if (tid < o) red[tid] += red[tid + o];
    __syncthreads();
  }
  double sumsq = red[0];
  __syncthreads();
  red[tid] = scs;
  __syncthreads();
  for (int o = 128; o > 0; o >>= 1) {
    if (tid < o) red[tid] += red[tid + o];
    __syncthreads();
  }
  if (tid == 0) {
    double n = (double)NROWS;
    double suml2 = 2.0 * n * sumsq - 2.0 * red[0];
    double bw = suml2 / (n * n - n);
    gout[0] = (float)(-1.0 / (16.0 * bw));
  }
}

// ---------- kernel C: triangle-tiled fp16 MFMA Gram, dbuf 2-phase, fused epilogue ----------
__global__ __launch_bounds__(256, 2) void mmd_gemm_kernel(
    const u16* __restrict__ hp,
    const float* __restrict__ sq, const float* __restrict__ gptr,
    float* __restrict__ partials) {
  __shared__ __align__(16) u16 sA[2][BM * BK];   // 2 x 16 KB
  __shared__ __align__(16) u16 sB[2][BM * BK];   // 2 x 16 KB
  __shared__ float sqR[BM], sqC[BM];

  // bijective XCD swizzle (2080 % 8 == 0), then linear-index -> triangle (I<=J)
  int bid = blockIdx.x;
  int t = (bid & 7) * (NTILES / 8) + (bid >> 3);
  int I = 0, rem = t;
  while (rem >= TT - I) { rem -= TT - I; ++I; }
  int J = I + rem;
  int rowStart = I * BM, colStart = J * BM;

  int tid = threadIdx.x;
  int lane = tid & 63, wid = tid >> 6;
  int wr = wid >> 1, wc = wid & 1;

  // staging setup: waves 0,1 -> A halves; waves 2,3 -> B halves.
  // per instr s (8 rows x 64 cols = 1KB): lane covers row (lane>>3), chunk (lane&7),
  // global chunk pre-swizzled by ^(row&7) so linear LDS holds swizzled layout.
  int w1 = wid & 1;
  int rstart = (wid < 2) ? rowStart : colStart;
  const u16* gp0 = hp + (size_t)(rstart + w1 * 64 + (lane >> 3)) * DCOL
                      + ((lane & 7) ^ (lane >> 3)) * 8;
  u16* ldsMat = (wid < 2) ? &sA[0][0] : &sB[0][0];

  // fragment read offsets (f16 units): addr = base + m*1024 + co[kk]
  int aBase0 = (wr * 64 + (lane & 15)) * BK;
  int bBase0 = (wc * 64 + (lane & 15)) * BK;
  int co0 = (((lane >> 4)) ^ (lane & 7)) * 8;        // kk=0
  int co1 = ((4 + (lane >> 4)) ^ (lane & 7)) * 8;    // kk=1

  f32x4 acc[4][4];
#pragma unroll
  for (int m = 0; m < 4; ++m)
#pragma unroll
    for (int n = 0; n < 4; ++n) acc[m][n] = (f32x4){0.f, 0.f, 0.f, 0.f};

  // prologue: stage K-tile 0 into buf 0
#pragma unroll
  for (int s = 0; s < 8; ++s) {
    const u16* gp = gp0 + (size_t)s * 8 * DCOL;
    u16* lp = ldsMat + (w1 * 64 + s * 8) * BK;
    __builtin_amdgcn_global_load_lds(
        (const __attribute__((address_space(1))) void*)gp,
        (__attribute__((address_space(3))) void*)lp, 16, 0, 0);
  }
  if (tid < BM) sqR[tid] = sq[rowStart + tid];
  else sqC[tid - BM] = sq[colStart + (tid - BM)];
  __syncthreads();

#pragma unroll
  for (int kt = 0; kt < KSTEPS; ++kt) {
    int cur = kt & 1;
    // phase 1: issue next K-tile's staging into the other buffer
    if (kt + 1 < KSTEPS) {
      int nxt = cur ^ 1;
      const u16* gpk = gp0 + (size_t)(kt + 1) * BK;
#pragma unroll
      for (int s = 0; s < 8; ++s) {
        const u16* gp = gpk + (size_t)s * 8 * DCOL;
        u16* lp = ldsMat + nxt * (BM * BK) + (w1 * 64 + s * 8) * BK;
        __builtin_amdgcn_global_load_lds(
            (const __attribute__((address_space(1))) void*)gp,
            (__attribute__((address_space(3))) void*)lp, 16, 0, 0);
      }
    }
    // phase 2: ds_read fragments of current tile
    f16x8 av0[4], av1[4], bv0[4], bv1[4];
#pragma unroll
    for (int m = 0; m < 4; ++m) {
      av0[m] = *reinterpret_cast<const f16x8*>(&sA[cur][aBase0 + m * 1024 + co0]);
      av1[m] = *reinterpret_cast<const f16x8*>(&sA[cur][aBase0 + m * 1024 + co1]);
    }
#pragma unroll
    for (int n = 0; n < 4; ++n) {
      bv0[n] = *reinterpret_cast<const f16x8*>(&sB[cur][bBase0 + n * 1024 + co0]);
      bv1[n] = *reinterpret_cast<const f16x8*>(&sB[cur][bBase0 + n * 1024 + co1]);
    }
    // phase 3: MFMA
#pragma unroll
    for (int m = 0; m < 4; ++m)
#pragma unroll
      for (int n = 0; n < 4; ++n) {
        acc[m][n] = __builtin_amdgcn_mfma_f32_16x16x32_f16(av0[m], bv0[n], acc[m][n], 0, 0, 0);
        acc[m][n] = __builtin_amdgcn_mfma_f32_16x16x32_f16(av1[m], bv1[n], acc[m][n], 0, 0, 0);
      }
    // phase 4: drain staging + release LDS for next overwrite
    __syncthreads();
  }

  // fused epilogue: l2 -> sum_k exp(-l2/(bw*2^k)) = u + u^2 + u^4 + u^8 + u^16
  float gf = gptr[0];
  float partial = 0.f;
  int rbase = (lane >> 4) * 4;
  int cidx = lane & 15;
#pragma unroll
  for (int m = 0; m < 4; ++m) {
    float sr[4];
#pragma unroll
    for (int e = 0; e < 4; ++e) sr[e] = sqR[wr * 64 + m * 16 + rbase + e];
#pragma unroll
    for (int n = 0; n < 4; ++n) {
      float sc = sqC[wc * 64 + n * 16 + cidx];
#pragma unroll
      for (int e = 0; e < 4; ++e) {
        float d = acc[m][n][e];
        float l2v = sr[e] + sc - 2.f * d;
        float u = __expf(gf * l2v);
        float u2 = u * u, u4 = u2 * u2, u8 = u4 * u4, u16v = u8 * u8;
        partial += u + u2 + u4 + u8 + u16v;
      }
    }
  }
  float wsign = ((I == J) ? 1.f : 2.f) *
                (((rowStart < B_HALF) == (colStart < B_HALF)) ? 1.f : -1.f);
  partial *= wsign;
#pragma unroll
  for (int o = 32; o > 0; o >>= 1) partial += __shfl_down(partial, o);
  if (lane == 0) partials[bid * 4 + wid] = partial;   // no same-address atomics
}

// ---------- kernel D: deterministic finalize ----------
__global__ void finalize_kernel(const float* __restrict__ partials,
                                float* __restrict__ out) {
  __shared__ double red[256];
  int tid = threadIdx.x;
  double s = 0.0;
  for (int i = tid; i < NTILES * 4; i += 256) s += (double)partials[i];
  red[tid] = s;
  __syncthreads();
  for (int o = 128; o > 0; o >>= 1) {
    if (tid < o) red[tid] += red[tid + o];
    __syncthreads();
  }
  if (tid == 0) out[0] = (float)(red[0] / (4096.0 * 4096.0));
}

extern "C" void kernel_launch(void* const* d_in, const int* in_sizes, int n_in,
                              void* d_out, int out_size, void* d_ws, size_t ws_size,
                              hipStream_t stream) {
  const float* src = (const float*)d_in[0];
  const float* tgt = (const float*)d_in[1];
  char* ws = (char*)d_ws;

  float* colsum   = (float*)(ws + 0);        // 512 f32 = 2 KB (memset to 0)
  float* gp       = (float*)(ws + 2048);     // 1 f32
  float* sqp      = (float*)(ws + 4096);     // 8192 f32 = 32 KB
  float* partials = (float*)(ws + 36864);    // 8320 f32 ~ 33 KB
  u16*   hp       = (u16*)(ws + 131072);     // 8192*512 fp16 = 8.39 MB

  hipMemsetAsync(ws, 0, 4096, stream);       // zero colsum (+g)

  prep_kernel<<<NROWS / 16, 256, 0, stream>>>(src, tgt, hp, sqp, colsum);
  bw_kernel<<<1, 256, 0, stream>>>(colsum, sqp, gp);
  mmd_gemm_kernel<<<NTILES, 256, 0, stream>>>(hp, sqp, gp, partials);
  finalize_kernel<<<1, 256, 0, stream>>>(partials, (float*)d_out);
}